// Round 9
// baseline (215.542 us; speedup 1.0000x reference)
//
#include <hip/hip_runtime.h>

#define DCH 128
#define T_PART 4096
#define B_MAX 512
#define CAPC 6144

typedef short bf16x8 __attribute__((ext_vector_type(8)));
typedef float f32x4 __attribute__((ext_vector_type(4)));

__device__ inline unsigned short f2bf(float f) {
    unsigned int u = __float_as_uint(f);
    unsigned int r = (u + 0x7fffu + ((u >> 16) & 1u)) >> 16;
    return (unsigned short)r;
}

__device__ inline void gload_lds16(const void* g, void* l) {
    __builtin_amdgcn_global_load_lds(
        (const __attribute__((address_space(1))) void*)g,
        (__attribute__((address_space(3))) void*)l, 16, 0, 0);
}

// -------- launch 1: part (blocks < nPart, 30.8 KB LDS -> 4 blk/CU) ----------
//          + Wf pack (4 trailing blocks; consumed only by the NEXT launch)
__global__ __launch_bounds__(512) void k_pg(const int* __restrict__ row,
                                            const int* __restrict__ col,
                                            unsigned int* __restrict__ coarse,
                                            int* __restrict__ gcount,
                                            const float* __restrict__ W,
                                            unsigned short* __restrict__ Wf,
                                            int E, int B, int nPart) {
    int tid = threadIdx.x;
    int wv = tid >> 6, lane = tid & 63;

    if (blockIdx.x >= nPart) {
        // ---- Wf pack: frag (nt,ks): lane holds B[k=ks*32+(lane>>4)*8+j][n=nt*16+(lane&15)]
        int frag = (blockIdx.x - nPart) * 8 + wv;
        if (frag < 32) {
            int nt = frag >> 2, ks = frag & 3;
            int nn = nt * 16 + (lane & 15);
            int k0 = ks * 32 + ((lane >> 4) * 8);
            unsigned short tmp[8];
#pragma unroll
            for (int j = 0; j < 8; ++j) tmp[j] = f2bf(W[(size_t)(k0 + j) * DCH + nn]);
            *(uint4*)&Wf[((size_t)frag * 64 + lane) * 8] = *(const uint4*)tmp;
        }
        return;
    }

    __shared__ unsigned int spack[T_PART];      // 16 KB
    __shared__ unsigned short sbuck[T_PART];    // 8 KB
    __shared__ int hist[B_MAX];                 // 2 KB (reused as gb)
    __shared__ int basex[B_MAX];                // 2 KB
    __shared__ int curx[B_MAX];                 // 2 KB
    __shared__ int wsum[8];
    int* gb = hist;

    int base_e = blockIdx.x * T_PART;
    int tileCnt = min(T_PART, E - base_e);

    hist[tid] = 0;
    __syncthreads();

    int er[8], ec[8];
#pragma unroll
    for (int i = 0; i < 8; ++i) {
        int e = base_e + tid + i * 512;
        if (e < E) {
            er[i] = row[e];
            ec[i] = col[e];
            atomicAdd(&hist[ec[i] >> 8], 1);
        } else {
            er[i] = -1;
            ec[i] = 0;
        }
    }
    __syncthreads();

    int v = hist[tid];
    int x2 = v;
#pragma unroll
    for (int o = 1; o < 64; o <<= 1) {
        int t = __shfl_up(x2, o, 64);
        if (lane >= o) x2 += t;
    }
    if (lane == 63) wsum[wv] = x2;
    __syncthreads();
    int add = 0;
    for (int w = 0; w < wv; ++w) add += wsum[w];
    int excl = x2 - v + add;
    basex[tid] = excl;
    curx[tid] = excl;
    gb[tid] = (tid < B && v > 0) ? atomicAdd(&gcount[tid], v) : 0;
    __syncthreads();

#pragma unroll
    for (int i = 0; i < 8; ++i) {
        if (er[i] >= 0) {
            int bb = ec[i] >> 8;
            int slot = atomicAdd(&curx[bb], 1);
            spack[slot] = ((unsigned int)er[i] << 8) | (unsigned int)(ec[i] & 255);
            sbuck[slot] = (unsigned short)bb;
        }
    }
    __syncthreads();

    for (int s = tid; s < tileCnt; s += 512) {
        int bb = sbuck[s];
        int dst = gb[bb] + (s - basex[bb]);
        if (dst < CAPC) coarse[(size_t)bb * CAPC + dst] = spack[s];
    }
}

// -------- launch 2: csr (blocks < B) || gemm (blocks >= B), 32 KB union -----
__global__ __launch_bounds__(512) void k_cg(const unsigned int* __restrict__ coarse,
                                            const int* __restrict__ gcount,
                                            int* __restrict__ srow,
                                            int* __restrict__ off,
                                            float* __restrict__ dinvf,
                                            const float* __restrict__ x,
                                            const unsigned short* __restrict__ Wf,
                                            unsigned short* __restrict__ y,
                                            int n, int B) {
    __shared__ uint4 smem4[2048];               // 32 KB union
    char* smem = (char*)smem4;

    int tid = threadIdx.x;
    int wv = tid >> 6, lane = tid & 63;

    if (blockIdx.x < B) {
        // ---------------- csr: bucket -> exact CSR + dinv + offsets ----------
        unsigned int* ent = (unsigned int*)smem;          // 24 KB
        int* h   = (int*)(smem + 24576);                  // 1 KB
        int* cur = (int*)(smem + 25600);                  // 1 KB
        int* red1 = (int*)(smem + 26624);                 // 32 B
        int* red2 = (int*)(smem + 26656);                 // 16 B
        int* bbase_p = (int*)(smem + 26672);

        int b = blockIdx.x;

        int part = 0;
        for (int i = tid; i < b; i += 512) part += gcount[i];
#pragma unroll
        for (int o = 1; o < 64; o <<= 1) part += __shfl_xor(part, o, 64);
        if (lane == 0) red1[wv] = part;
        if (tid < 256) h[tid] = 0;
        __syncthreads();
        if (tid == 0) {
            int s = 0;
            for (int w = 0; w < 8; ++w) s += red1[w];
            bbase_p[0] = s;
        }
        int cntb = min(gcount[b], CAPC);
        for (int s = tid; s < cntb; s += 512) ent[s] = coarse[(size_t)b * CAPC + s];
        __syncthreads();

        for (int s = tid; s < cntb; s += 512) atomicAdd(&h[ent[s] & 255], 1);
        __syncthreads();

        int x2 = 0, v = 0;
        if (tid < 256) {
            v = h[tid];
            x2 = v;
#pragma unroll
            for (int o = 1; o < 64; o <<= 1) {
                int t = __shfl_up(x2, o, 64);
                if (lane >= o) x2 += t;
            }
            if (lane == 63) red2[wv] = x2;
        }
        __syncthreads();
        int bbase = bbase_p[0];
        if (tid < 256) {
            int add = 0;
            for (int w = 0; w < wv; ++w) add += red2[w];
            int excl = x2 - v + add;
            cur[tid] = excl;
            int node = (b << 8) + tid;
            if (node < n) {
                off[node] = bbase + excl;
                dinvf[node] = rsqrtf((float)(v + 1));
            }
        }
        __syncthreads();

        for (int s = tid; s < cntb; s += 512) {
            unsigned int p = ent[s];
            int d = p & 255;
            int slot = atomicAdd(&cur[d], 1);
            srow[bbase + slot] = (int)(p >> 8);
        }
    } else {
        // ---------------- gemm: y = bf16(x @ W), 64 rows/block ---------------
        int blockRow = (blockIdx.x - B) * 64;

        // stage 64 rows x 512 B = 32 KB: linear LDS dest, pre-swizzled source
#pragma unroll
        for (int t = 0; t < 4; ++t) {
            int off2 = t * 8192 + wv * 1024 + lane * 16;
            int r = off2 >> 9;                            // tile row 0..63
            int gr = blockRow + r;
            if (gr >= n) gr = n - 1;
            int colb = (off2 & 511) ^ ((r & 7) << 4);     // pre-swizzled source
            const char* src = (const char*)x + (size_t)gr * 512 + colb;
            char* dst = smem + t * 8192 + wv * 1024;
            gload_lds16(src, dst);
        }
        __syncthreads();

        f32x4 acc[4];
        f32x4 zero = {0.f, 0.f, 0.f, 0.f};
#pragma unroll
        for (int t = 0; t < 4; ++t) acc[t] = zero;

        const bf16x8* wfv = (const bf16x8*)Wf;
        int rowL = (wv >> 1) * 16 + (lane & 15);   // row-tile shared by 2 waves
        int ntBase = (wv & 1) * 4;                 // column-half split
        int q = lane >> 4;
        int swz = (rowL & 7) << 4;
#pragma unroll
        for (int ks = 0; ks < 4; ++ks) {
            int colb = ks * 128 + q * 32;
            float4 lo = *(const float4*)&smem[(rowL * 512 + colb) ^ swz];
            float4 hi = *(const float4*)&smem[(rowL * 512 + colb + 16) ^ swz];
            bf16x8 a;
            a[0] = (short)f2bf(lo.x); a[1] = (short)f2bf(lo.y);
            a[2] = (short)f2bf(lo.z); a[3] = (short)f2bf(lo.w);
            a[4] = (short)f2bf(hi.x); a[5] = (short)f2bf(hi.y);
            a[6] = (short)f2bf(hi.z); a[7] = (short)f2bf(hi.w);
#pragma unroll
            for (int nt2 = 0; nt2 < 4; ++nt2) {
                int nt = ntBase + nt2;
                bf16x8 bfr = wfv[(nt * 4 + ks) * 64 + lane];
                acc[nt2] = __builtin_amdgcn_mfma_f32_16x16x32_bf16(a, bfr, acc[nt2], 0, 0, 0);
            }
        }

        int rowBase = blockRow + (wv >> 1) * 16;
        int orow_base = rowBase + q * 4;
#pragma unroll
        for (int r = 0; r < 4; ++r) {
            int orow = orow_base + r;
            if (orow < n) {
#pragma unroll
                for (int nt2 = 0; nt2 < 4; ++nt2) {
                    int nt = ntBase + nt2;
                    y[(size_t)orow * DCH + nt * 16 + (lane & 15)] = f2bf(acc[nt2][r]);
                }
            }
        }
    }
}

// ---------------- per-node gather-aggregate + bias + ReLU --------------------
// R9: processes node range [i0, i0+chunk) — k_agg is split into 4 quarter
// launches (~17 µs each) so any pre-kernel >17 µs surfaces in the top-5
// profile with full counters (attribution experiment; same total work).
__global__ __launch_bounds__(256) void k_agg(const uint4* __restrict__ y4,
                                             const int* __restrict__ srow,
                                             const int* __restrict__ off,
                                             const float* __restrict__ dinv,
                                             const float* __restrict__ b,
                                             float* __restrict__ out, int n, int E,
                                             int i0, int i1) {
    int i = i0 + blockIdx.x * 4 + (threadIdx.x >> 6);
    if (i >= i1) return;
    int lane = threadIdx.x & 63;
    int q = lane >> 4;
    int l16 = lane & 15;
    int s = off[i];
    int e = (i + 1 < n) ? off[i + 1] : E;
    float di = dinv[i];

    float acc[8];
#pragma unroll
    for (int k = 0; k < 8; ++k) acc[k] = 0.f;

    if (q == 0) {   // self-loop: dinv_i * z_i
        uint4 v = y4[(size_t)i * 16 + l16];
        unsigned int p[4] = {v.x, v.y, v.z, v.w};
#pragma unroll
        for (int t = 0; t < 4; ++t) {
            acc[2 * t]     = fmaf(di, __uint_as_float(p[t] << 16), acc[2 * t]);
            acc[2 * t + 1] = fmaf(di, __uint_as_float(p[t] & 0xffff0000u), acc[2 * t + 1]);
        }
    }

    int j = s;
    for (; j + 16 <= e; j += 16) {
        int s0 = srow[j + q];
        int s1 = srow[j + 4 + q];
        int s2 = srow[j + 8 + q];
        int s3 = srow[j + 12 + q];
        float d0 = dinv[s0], d1 = dinv[s1], d2 = dinv[s2], d3 = dinv[s3];
        uint4 v0 = y4[(size_t)s0 * 16 + l16];
        uint4 v1 = y4[(size_t)s1 * 16 + l16];
        uint4 v2 = y4[(size_t)s2 * 16 + l16];
        uint4 v3 = y4[(size_t)s3 * 16 + l16];
        unsigned int p0[4] = {v0.x, v0.y, v0.z, v0.w};
        unsigned int p1[4] = {v1.x, v1.y, v1.z, v1.w};
        unsigned int p2[4] = {v2.x, v2.y, v2.z, v2.w};
        unsigned int p3[4] = {v3.x, v3.y, v3.z, v3.w};
#pragma unroll
        for (int t = 0; t < 4; ++t) {
            acc[2 * t]     = fmaf(d0, __uint_as_float(p0[t] << 16), acc[2 * t]);
            acc[2 * t + 1] = fmaf(d0, __uint_as_float(p0[t] & 0xffff0000u), acc[2 * t + 1]);
            acc[2 * t]     = fmaf(d1, __uint_as_float(p1[t] << 16), acc[2 * t]);
            acc[2 * t + 1] = fmaf(d1, __uint_as_float(p1[t] & 0xffff0000u), acc[2 * t + 1]);
            acc[2 * t]     = fmaf(d2, __uint_as_float(p2[t] << 16), acc[2 * t]);
            acc[2 * t + 1] = fmaf(d2, __uint_as_float(p2[t] & 0xffff0000u), acc[2 * t + 1]);
            acc[2 * t]     = fmaf(d3, __uint_as_float(p3[t] << 16), acc[2 * t]);
            acc[2 * t + 1] = fmaf(d3, __uint_as_float(p3[t] & 0xffff0000u), acc[2 * t + 1]);
        }
    }
    for (; j + 8 <= e; j += 8) {
        int s0 = srow[j + q];
        int s1 = srow[j + 4 + q];
        float d0 = dinv[s0], d1 = dinv[s1];
        uint4 v0 = y4[(size_t)s0 * 16 + l16];
        uint4 v1 = y4[(size_t)s1 * 16 + l16];
        unsigned int p0[4] = {v0.x, v0.y, v0.z, v0.w};
        unsigned int p1[4] = {v1.x, v1.y, v1.z, v1.w};
#pragma unroll
        for (int t = 0; t < 4; ++t) {
            acc[2 * t]     = fmaf(d0, __uint_as_float(p0[t] << 16), acc[2 * t]);
            acc[2 * t + 1] = fmaf(d0, __uint_as_float(p0[t] & 0xffff0000u), acc[2 * t + 1]);
            acc[2 * t]     = fmaf(d1, __uint_as_float(p1[t] << 16), acc[2 * t]);
            acc[2 * t + 1] = fmaf(d1, __uint_as_float(p1[t] & 0xffff0000u), acc[2 * t + 1]);
        }
    }
    for (; j + 4 <= e; j += 4) {
        int s0 = srow[j + q];
        float d0 = dinv[s0];
        uint4 v0 = y4[(size_t)s0 * 16 + l16];
        unsigned int p0[4] = {v0.x, v0.y, v0.z, v0.w};
#pragma unroll
        for (int t = 0; t < 4; ++t) {
            acc[2 * t]     = fmaf(d0, __uint_as_float(p0[t] << 16), acc[2 * t]);
            acc[2 * t + 1] = fmaf(d0, __uint_as_float(p0[t] & 0xffff0000u), acc[2 * t + 1]);
        }
    }
    if (j + q < e) {
        int s0 = srow[j + q];
        float d0 = dinv[s0];
        uint4 v0 = y4[(size_t)s0 * 16 + l16];
        unsigned int p0[4] = {v0.x, v0.y, v0.z, v0.w};
#pragma unroll
        for (int t = 0; t < 4; ++t) {
            acc[2 * t]     = fmaf(d0, __uint_as_float(p0[t] << 16), acc[2 * t]);
            acc[2 * t + 1] = fmaf(d0, __uint_as_float(p0[t] & 0xffff0000u), acc[2 * t + 1]);
        }
    }

#pragma unroll
    for (int k = 0; k < 8; ++k) {
        acc[k] += __shfl_xor(acc[k], 16, 64);
        acc[k] += __shfl_xor(acc[k], 32, 64);
    }

    if (q == 0) {
        float sc = di;
        int c0 = l16 * 8;
        float4 b0 = *(const float4*)&b[c0];
        float4 b1 = *(const float4*)&b[c0 + 4];
        f32x4 o0, o1;
        o0[0] = fmaxf(fmaf(sc, acc[0], b0.x), 0.f);
        o0[1] = fmaxf(fmaf(sc, acc[1], b0.y), 0.f);
        o0[2] = fmaxf(fmaf(sc, acc[2], b0.z), 0.f);
        o0[3] = fmaxf(fmaf(sc, acc[3], b0.w), 0.f);
        o1[0] = fmaxf(fmaf(sc, acc[4], b1.x), 0.f);
        o1[1] = fmaxf(fmaf(sc, acc[5], b1.y), 0.f);
        o1[2] = fmaxf(fmaf(sc, acc[6], b1.z), 0.f);
        o1[3] = fmaxf(fmaf(sc, acc[7], b1.w), 0.f);
        f32x4* orow = (f32x4*)&out[(size_t)i * DCH + c0];
        __builtin_nontemporal_store(o0, &orow[0]);
        __builtin_nontemporal_store(o1, &orow[1]);
    }
}

extern "C" void kernel_launch(void* const* d_in, const int* in_sizes, int n_in,
                              void* d_out, int out_size, void* d_ws, size_t ws_size,
                              hipStream_t stream) {
    const float* x = (const float*)d_in[0];
    const int* ei  = (const int*)d_in[1];
    const float* W = (const float*)d_in[2];
    const float* b = (const float*)d_in[3];
    float* out = (float*)d_out;

    int n = in_sizes[0] / DCH;     // 100000
    int E = in_sizes[1] / 2;       // 1600000
    const int* row = ei;           // sources
    const int* col = ei + E;       // destinations

    int B = (n + 255) / 256;       // 391 coarse buckets

    char* ws = (char*)d_ws;
    size_t o = 0;
    auto alloc = [&](size_t bytes) -> void* {
        o = (o + 255) & ~(size_t)255;
        void* p = ws + o;
        o += bytes;
        return p;
    };
    float* dinvf = (float*)alloc((size_t)n * 4);
    int* off     = (int*)alloc((size_t)(n + 1) * 4);
    int* gcount  = (int*)alloc((size_t)B * 4);
    int* srow    = (int*)alloc((size_t)E * 4);
    unsigned int* coarse = (unsigned int*)alloc((size_t)B * CAPC * 4);  // 9.6 MB
    unsigned short* Wf = (unsigned short*)alloc((size_t)DCH * DCH * 2);
    unsigned short* y  = (unsigned short*)alloc((size_t)n * DCH * 2);   // 25.6 MB

    int nt = (E + T_PART - 1) / T_PART;        // 391 part blocks
    int gemmBlocks = (n + 63) / 64;            // 1563 gemm blocks

    hipMemsetAsync(gcount, 0, (size_t)B * 4, stream);
    k_pg<<<nt + 4, 512, 0, stream>>>(row, col, coarse, gcount, W, Wf, E, B, nt);
    k_cg<<<B + gemmBlocks, 512, 0, stream>>>(coarse, gcount, srow, off, dinvf,
                                             x, Wf, y, n, B);

    // agg split into 4 quarter launches (attribution: surfaces pre-kernels
    // >17 µs in the top-5 profile; same total work as one launch)
    int chunk = ((n + 3) / 4 + 3) & ~3;        // multiple of 4 nodes
    for (int qtr = 0; qtr < 4; ++qtr) {
        int i0 = qtr * chunk;
        if (i0 >= n) break;
        int i1 = min(i0 + chunk, n);
        int blocks = (i1 - i0 + 3) / 4;
        k_agg<<<blocks, 256, 0, stream>>>((const uint4*)y, srow, off, dinvf,
                                          b, out, n, E, i0, i1);
    }
}

// Round 10
// 204.252 us; speedup vs baseline: 1.0553x; 1.0553x over previous
//
#include <hip/hip_runtime.h>

#define DCH 128
#define T_PART 4096
#define B_MAX 512
#define CAPC 6144

typedef short bf16x8 __attribute__((ext_vector_type(8)));
typedef float f32x4 __attribute__((ext_vector_type(4)));

__device__ inline unsigned short f2bf(float f) {
    unsigned int u = __float_as_uint(f);
    unsigned int r = (u + 0x7fffu + ((u >> 16) & 1u)) >> 16;
    return (unsigned short)r;
}

__device__ inline void gload_lds16(const void* g, void* l) {
    __builtin_amdgcn_global_load_lds(
        (const __attribute__((address_space(1))) void*)g,
        (__attribute__((address_space(3))) void*)l, 16, 0, 0);
}

// -------- launch 1: part (blocks < nPart) + Wf pack (4 trailing blocks) ------
// R10 part: direct-scatter form. hist -> global range reserve -> per-edge LDS
// rank atomic -> direct 4 B store into the bucket's reserved range. The LDS
// re-pack (spack/sbuck + scan + re-read + grouped write) is deleted: each
// (tile,bucket) range is contiguous either way, and L2 write-combines the
// block's scatters within bucket regions. LDS 30.8 KB -> 4 KB; 2 fewer
// barriers; scan eliminated.
__global__ __launch_bounds__(512) void k_pg(const int* __restrict__ row,
                                            const int* __restrict__ col,
                                            unsigned int* __restrict__ coarse,
                                            int* __restrict__ gcount,
                                            const float* __restrict__ W,
                                            unsigned short* __restrict__ Wf,
                                            int E, int B, int nPart) {
    int tid = threadIdx.x;
    int wv = tid >> 6, lane = tid & 63;

    if (blockIdx.x >= nPart) {
        // ---- Wf pack: frag (nt,ks): lane holds B[k=ks*32+(lane>>4)*8+j][n=nt*16+(lane&15)]
        int frag = (blockIdx.x - nPart) * 8 + wv;
        if (frag < 32) {
            int nt = frag >> 2, ks = frag & 3;
            int nn = nt * 16 + (lane & 15);
            int k0 = ks * 32 + ((lane >> 4) * 8);
            unsigned short tmp[8];
#pragma unroll
            for (int j = 0; j < 8; ++j) tmp[j] = f2bf(W[(size_t)(k0 + j) * DCH + nn]);
            *(uint4*)&Wf[((size_t)frag * 64 + lane) * 8] = *(const uint4*)tmp;
        }
        return;
    }

    __shared__ int hist[B_MAX];                 // 2 KB
    __shared__ int curx[B_MAX];                 // 2 KB

    int base_e = blockIdx.x * T_PART;

    hist[tid] = 0;
    __syncthreads();

    int er[8], ec[8];
#pragma unroll
    for (int i = 0; i < 8; ++i) {
        int e = base_e + tid + i * 512;
        if (e < E) {
            er[i] = row[e];
            ec[i] = col[e];
            atomicAdd(&hist[ec[i] >> 8], 1);
        } else {
            er[i] = -1;
            ec[i] = 0;
        }
    }
    __syncthreads();

    int v = hist[tid];
    curx[tid] = (tid < B && v > 0) ? atomicAdd(&gcount[tid], v) : 0;
    __syncthreads();

#pragma unroll
    for (int i = 0; i < 8; ++i) {
        if (er[i] >= 0) {
            int bb = ec[i] >> 8;
            int slot = atomicAdd(&curx[bb], 1);   // global index within bucket
            if (slot < CAPC)
                coarse[(size_t)bb * CAPC + slot] =
                    ((unsigned int)er[i] << 8) | (unsigned int)(ec[i] & 255);
        }
    }
}

// -------- launch 2: csr (blocks < B) || gemm (blocks >= B), 32 KB union -----
// csr is the only consumer of part's output; gemm (BW-bound) hides it.
__global__ __launch_bounds__(512) void k_cg(const unsigned int* __restrict__ coarse,
                                            const int* __restrict__ gcount,
                                            int* __restrict__ srow,
                                            int* __restrict__ off,
                                            float* __restrict__ dinvf,
                                            const float* __restrict__ x,
                                            const unsigned short* __restrict__ Wf,
                                            unsigned short* __restrict__ y,
                                            int n, int B) {
    __shared__ uint4 smem4[2048];               // 32 KB union
    char* smem = (char*)smem4;

    int tid = threadIdx.x;
    int wv = tid >> 6, lane = tid & 63;

    if (blockIdx.x < B) {
        // ---------------- csr: bucket -> exact CSR + dinv + offsets ----------
        unsigned int* ent = (unsigned int*)smem;          // 24 KB
        int* h   = (int*)(smem + 24576);                  // 1 KB
        int* cur = (int*)(smem + 25600);                  // 1 KB
        int* red1 = (int*)(smem + 26624);                 // 32 B
        int* red2 = (int*)(smem + 26656);                 // 16 B
        int* bbase_p = (int*)(smem + 26672);

        int b = blockIdx.x;

        int part = 0;
        for (int i = tid; i < b; i += 512) part += gcount[i];
#pragma unroll
        for (int o = 1; o < 64; o <<= 1) part += __shfl_xor(part, o, 64);
        if (lane == 0) red1[wv] = part;
        if (tid < 256) h[tid] = 0;
        __syncthreads();
        if (tid == 0) {
            int s = 0;
            for (int w = 0; w < 8; ++w) s += red1[w];
            bbase_p[0] = s;
        }
        int cntb = min(gcount[b], CAPC);
        for (int s = tid; s < cntb; s += 512) ent[s] = coarse[(size_t)b * CAPC + s];
        __syncthreads();

        for (int s = tid; s < cntb; s += 512) atomicAdd(&h[ent[s] & 255], 1);
        __syncthreads();

        int x2 = 0, v = 0;
        if (tid < 256) {
            v = h[tid];
            x2 = v;
#pragma unroll
            for (int o = 1; o < 64; o <<= 1) {
                int t = __shfl_up(x2, o, 64);
                if (lane >= o) x2 += t;
            }
            if (lane == 63) red2[wv] = x2;
        }
        __syncthreads();
        int bbase = bbase_p[0];
        if (tid < 256) {
            int add = 0;
            for (int w = 0; w < wv; ++w) add += red2[w];
            int excl = x2 - v + add;
            cur[tid] = excl;
            int node = (b << 8) + tid;
            if (node < n) {
                off[node] = bbase + excl;
                dinvf[node] = rsqrtf((float)(v + 1));
            }
        }
        __syncthreads();

        for (int s = tid; s < cntb; s += 512) {
            unsigned int p = ent[s];
            int d = p & 255;
            int slot = atomicAdd(&cur[d], 1);
            srow[bbase + slot] = (int)(p >> 8);
        }
    } else {
        // ---------------- gemm: y = bf16(x @ W), 64 rows/block ---------------
        int blockRow = (blockIdx.x - B) * 64;

        // stage 64 rows x 512 B = 32 KB: linear LDS dest, pre-swizzled source
#pragma unroll
        for (int t = 0; t < 4; ++t) {
            int off2 = t * 8192 + wv * 1024 + lane * 16;
            int r = off2 >> 9;                            // tile row 0..63
            int gr = blockRow + r;
            if (gr >= n) gr = n - 1;
            int colb = (off2 & 511) ^ ((r & 7) << 4);     // pre-swizzled source
            const char* src = (const char*)x + (size_t)gr * 512 + colb;
            char* dst = smem + t * 8192 + wv * 1024;
            gload_lds16(src, dst);
        }
        __syncthreads();

        f32x4 acc[4];
        f32x4 zero = {0.f, 0.f, 0.f, 0.f};
#pragma unroll
        for (int t = 0; t < 4; ++t) acc[t] = zero;

        const bf16x8* wfv = (const bf16x8*)Wf;
        int rowL = (wv >> 1) * 16 + (lane & 15);   // row-tile shared by 2 waves
        int ntBase = (wv & 1) * 4;                 // column-half split
        int q = lane >> 4;
        int swz = (rowL & 7) << 4;
#pragma unroll
        for (int ks = 0; ks < 4; ++ks) {
            int colb = ks * 128 + q * 32;
            float4 lo = *(const float4*)&smem[(rowL * 512 + colb) ^ swz];
            float4 hi = *(const float4*)&smem[(rowL * 512 + colb + 16) ^ swz];
            bf16x8 a;
            a[0] = (short)f2bf(lo.x); a[1] = (short)f2bf(lo.y);
            a[2] = (short)f2bf(lo.z); a[3] = (short)f2bf(lo.w);
            a[4] = (short)f2bf(hi.x); a[5] = (short)f2bf(hi.y);
            a[6] = (short)f2bf(hi.z); a[7] = (short)f2bf(hi.w);
#pragma unroll
            for (int nt2 = 0; nt2 < 4; ++nt2) {
                int nt = ntBase + nt2;
                bf16x8 bfr = wfv[(nt * 4 + ks) * 64 + lane];
                acc[nt2] = __builtin_amdgcn_mfma_f32_16x16x32_bf16(a, bfr, acc[nt2], 0, 0, 0);
            }
        }

        int rowBase = blockRow + (wv >> 1) * 16;
        int orow_base = rowBase + q * 4;
#pragma unroll
        for (int r = 0; r < 4; ++r) {
            int orow = orow_base + r;
            if (orow < n) {
#pragma unroll
                for (int nt2 = 0; nt2 < 4; ++nt2) {
                    int nt = ntBase + nt2;
                    y[(size_t)orow * DCH + nt * 16 + (lane & 15)] = f2bf(acc[nt2][r]);
                }
            }
        }
    }
}

// ---------------- per-node gather-aggregate + bias + ReLU --------------------
// One wave per node; quarter-wave q handles edge j+q via uint4 loads; per-edge
// source dinv from L2-resident table via fmaf. shfl_xor(16/32) folds quarters.
__global__ __launch_bounds__(256) void k_agg(const uint4* __restrict__ y4,
                                             const int* __restrict__ srow,
                                             const int* __restrict__ off,
                                             const float* __restrict__ dinv,
                                             const float* __restrict__ b,
                                             float* __restrict__ out, int n, int E) {
    int i = blockIdx.x * 4 + (threadIdx.x >> 6);
    if (i >= n) return;
    int lane = threadIdx.x & 63;
    int q = lane >> 4;
    int l16 = lane & 15;
    int s = off[i];
    int e = (i + 1 < n) ? off[i + 1] : E;
    float di = dinv[i];

    float acc[8];
#pragma unroll
    for (int k = 0; k < 8; ++k) acc[k] = 0.f;

    if (q == 0) {   // self-loop: dinv_i * z_i
        uint4 v = y4[(size_t)i * 16 + l16];
        unsigned int p[4] = {v.x, v.y, v.z, v.w};
#pragma unroll
        for (int t = 0; t < 4; ++t) {
            acc[2 * t]     = fmaf(di, __uint_as_float(p[t] << 16), acc[2 * t]);
            acc[2 * t + 1] = fmaf(di, __uint_as_float(p[t] & 0xffff0000u), acc[2 * t + 1]);
        }
    }

    int j = s;
    for (; j + 16 <= e; j += 16) {
        int s0 = srow[j + q];
        int s1 = srow[j + 4 + q];
        int s2 = srow[j + 8 + q];
        int s3 = srow[j + 12 + q];
        float d0 = dinv[s0], d1 = dinv[s1], d2 = dinv[s2], d3 = dinv[s3];
        uint4 v0 = y4[(size_t)s0 * 16 + l16];
        uint4 v1 = y4[(size_t)s1 * 16 + l16];
        uint4 v2 = y4[(size_t)s2 * 16 + l16];
        uint4 v3 = y4[(size_t)s3 * 16 + l16];
        unsigned int p0[4] = {v0.x, v0.y, v0.z, v0.w};
        unsigned int p1[4] = {v1.x, v1.y, v1.z, v1.w};
        unsigned int p2[4] = {v2.x, v2.y, v2.z, v2.w};
        unsigned int p3[4] = {v3.x, v3.y, v3.z, v3.w};
#pragma unroll
        for (int t = 0; t < 4; ++t) {
            acc[2 * t]     = fmaf(d0, __uint_as_float(p0[t] << 16), acc[2 * t]);
            acc[2 * t + 1] = fmaf(d0, __uint_as_float(p0[t] & 0xffff0000u), acc[2 * t + 1]);
            acc[2 * t]     = fmaf(d1, __uint_as_float(p1[t] << 16), acc[2 * t]);
            acc[2 * t + 1] = fmaf(d1, __uint_as_float(p1[t] & 0xffff0000u), acc[2 * t + 1]);
            acc[2 * t]     = fmaf(d2, __uint_as_float(p2[t] << 16), acc[2 * t]);
            acc[2 * t + 1] = fmaf(d2, __uint_as_float(p2[t] & 0xffff0000u), acc[2 * t + 1]);
            acc[2 * t]     = fmaf(d3, __uint_as_float(p3[t] << 16), acc[2 * t]);
            acc[2 * t + 1] = fmaf(d3, __uint_as_float(p3[t] & 0xffff0000u), acc[2 * t + 1]);
        }
    }
    for (; j + 8 <= e; j += 8) {
        int s0 = srow[j + q];
        int s1 = srow[j + 4 + q];
        float d0 = dinv[s0], d1 = dinv[s1];
        uint4 v0 = y4[(size_t)s0 * 16 + l16];
        uint4 v1 = y4[(size_t)s1 * 16 + l16];
        unsigned int p0[4] = {v0.x, v0.y, v0.z, v0.w};
        unsigned int p1[4] = {v1.x, v1.y, v1.z, v1.w};
#pragma unroll
        for (int t = 0; t < 4; ++t) {
            acc[2 * t]     = fmaf(d0, __uint_as_float(p0[t] << 16), acc[2 * t]);
            acc[2 * t + 1] = fmaf(d0, __uint_as_float(p0[t] & 0xffff0000u), acc[2 * t + 1]);
            acc[2 * t]     = fmaf(d1, __uint_as_float(p1[t] << 16), acc[2 * t]);
            acc[2 * t + 1] = fmaf(d1, __uint_as_float(p1[t] & 0xffff0000u), acc[2 * t + 1]);
        }
    }
    for (; j + 4 <= e; j += 4) {
        int s0 = srow[j + q];
        float d0 = dinv[s0];
        uint4 v0 = y4[(size_t)s0 * 16 + l16];
        unsigned int p0[4] = {v0.x, v0.y, v0.z, v0.w};
#pragma unroll
        for (int t = 0; t < 4; ++t) {
            acc[2 * t]     = fmaf(d0, __uint_as_float(p0[t] << 16), acc[2 * t]);
            acc[2 * t + 1] = fmaf(d0, __uint_as_float(p0[t] & 0xffff0000u), acc[2 * t + 1]);
        }
    }
    if (j + q < e) {
        int s0 = srow[j + q];
        float d0 = dinv[s0];
        uint4 v0 = y4[(size_t)s0 * 16 + l16];
        unsigned int p0[4] = {v0.x, v0.y, v0.z, v0.w};
#pragma unroll
        for (int t = 0; t < 4; ++t) {
            acc[2 * t]     = fmaf(d0, __uint_as_float(p0[t] << 16), acc[2 * t]);
            acc[2 * t + 1] = fmaf(d0, __uint_as_float(p0[t] & 0xffff0000u), acc[2 * t + 1]);
        }
    }

#pragma unroll
    for (int k = 0; k < 8; ++k) {
        acc[k] += __shfl_xor(acc[k], 16, 64);
        acc[k] += __shfl_xor(acc[k], 32, 64);
    }

    if (q == 0) {
        float sc = di;
        int c0 = l16 * 8;
        float4 b0 = *(const float4*)&b[c0];
        float4 b1 = *(const float4*)&b[c0 + 4];
        f32x4 o0, o1;
        o0[0] = fmaxf(fmaf(sc, acc[0], b0.x), 0.f);
        o0[1] = fmaxf(fmaf(sc, acc[1], b0.y), 0.f);
        o0[2] = fmaxf(fmaf(sc, acc[2], b0.z), 0.f);
        o0[3] = fmaxf(fmaf(sc, acc[3], b0.w), 0.f);
        o1[0] = fmaxf(fmaf(sc, acc[4], b1.x), 0.f);
        o1[1] = fmaxf(fmaf(sc, acc[5], b1.y), 0.f);
        o1[2] = fmaxf(fmaf(sc, acc[6], b1.z), 0.f);
        o1[3] = fmaxf(fmaf(sc, acc[7], b1.w), 0.f);
        f32x4* orow = (f32x4*)&out[(size_t)i * DCH + c0];
        __builtin_nontemporal_store(o0, &orow[0]);
        __builtin_nontemporal_store(o1, &orow[1]);
    }
}

extern "C" void kernel_launch(void* const* d_in, const int* in_sizes, int n_in,
                              void* d_out, int out_size, void* d_ws, size_t ws_size,
                              hipStream_t stream) {
    const float* x = (const float*)d_in[0];
    const int* ei  = (const int*)d_in[1];
    const float* W = (const float*)d_in[2];
    const float* b = (const float*)d_in[3];
    float* out = (float*)d_out;

    int n = in_sizes[0] / DCH;     // 100000
    int E = in_sizes[1] / 2;       // 1600000
    const int* row = ei;           // sources
    const int* col = ei + E;       // destinations

    int B = (n + 255) / 256;       // 391 coarse buckets

    char* ws = (char*)d_ws;
    size_t o = 0;
    auto alloc = [&](size_t bytes) -> void* {
        o = (o + 255) & ~(size_t)255;
        void* p = ws + o;
        o += bytes;
        return p;
    };
    float* dinvf = (float*)alloc((size_t)n * 4);
    int* off     = (int*)alloc((size_t)(n + 1) * 4);
    int* gcount  = (int*)alloc((size_t)B * 4);
    int* srow    = (int*)alloc((size_t)E * 4);
    unsigned int* coarse = (unsigned int*)alloc((size_t)B * CAPC * 4);  // 9.6 MB
    unsigned short* Wf = (unsigned short*)alloc((size_t)DCH * DCH * 2);
    unsigned short* y  = (unsigned short*)alloc((size_t)n * DCH * 2);   // 25.6 MB

    int nt = (E + T_PART - 1) / T_PART;        // 391 part blocks
    int gemmBlocks = (n + 63) / 64;            // 1563 gemm blocks

    hipMemsetAsync(gcount, 0, (size_t)B * 4, stream);
    k_pg<<<nt + 4, 512, 0, stream>>>(row, col, coarse, gcount, W, Wf, E, B, nt);
    k_cg<<<B + gemmBlocks, 512, 0, stream>>>(coarse, gcount, srow, off, dinvf,
                                             x, Wf, y, n, B);
    k_agg<<<(n + 3) / 4, 256, 0, stream>>>((const uint4*)y, srow, off, dinvf,
                                           b, out, n, E);
}

// Round 11
// 201.249 us; speedup vs baseline: 1.0710x; 1.0149x over previous
//
#include <hip/hip_runtime.h>

#define DCH 128
#define T_PART 4096
#define B_MAX 512
#define CAPC 6144

typedef short bf16x8 __attribute__((ext_vector_type(8)));
typedef float f32x4 __attribute__((ext_vector_type(4)));

__device__ inline unsigned short f2bf(float f) {
    unsigned int u = __float_as_uint(f);
    unsigned int r = (u + 0x7fffu + ((u >> 16) & 1u)) >> 16;
    return (unsigned short)r;
}

__device__ inline void gload_lds16(const void* g, void* l) {
    __builtin_amdgcn_global_load_lds(
        (const __attribute__((address_space(1))) void*)g,
        (__attribute__((address_space(3))) void*)l, 16, 0, 0);
}

// ---------------- launch 0: zero gcount + pack W into MFMA B-frag order -----
// Replaces the hipMemsetAsync enqueue; Wf is consumed from launch 1 onward.
__global__ __launch_bounds__(256) void k_init(const float* __restrict__ W,
                                              unsigned short* __restrict__ Wf,
                                              int* __restrict__ gcount, int B) {
    int idx = blockIdx.x * 256 + threadIdx.x;
    if (idx < B) gcount[idx] = 0;
    int frag = blockIdx.x * 4 + (threadIdx.x >> 6);   // 8 blocks x 4 frags
    if (frag < 32) {
        int lane = threadIdx.x & 63;
        int nt = frag >> 2, ks = frag & 3;
        int nn = nt * 16 + (lane & 15);
        int k0 = ks * 32 + ((lane >> 4) * 8);
        unsigned short tmp[8];
#pragma unroll
        for (int j = 0; j < 8; ++j) tmp[j] = f2bf(W[(size_t)(k0 + j) * DCH + nn]);
        *(uint4*)&Wf[((size_t)frag * 64 + lane) * 8] = *(const uint4*)tmp;
    }
}

// ---------------- shared gemm tile body: y = bf16(x @ W), 64 rows -----------
__device__ inline void gemm_tile(char* smem, const float* __restrict__ x,
                                 const unsigned short* __restrict__ Wf,
                                 unsigned short* __restrict__ y,
                                 int blockRow, int n, int wv, int lane) {
    // stage 64 rows x 512 B = 32 KB: linear LDS dest, pre-swizzled source
#pragma unroll
    for (int t = 0; t < 4; ++t) {
        int off2 = t * 8192 + wv * 1024 + lane * 16;
        int r = off2 >> 9;                            // tile row 0..63
        int gr = blockRow + r;
        if (gr >= n) gr = n - 1;
        int colb = (off2 & 511) ^ ((r & 7) << 4);     // pre-swizzled source
        const char* src = (const char*)x + (size_t)gr * 512 + colb;
        char* dst = smem + t * 8192 + wv * 1024;
        gload_lds16(src, dst);
    }
    __syncthreads();

    f32x4 acc[4];
    f32x4 zero = {0.f, 0.f, 0.f, 0.f};
#pragma unroll
    for (int t = 0; t < 4; ++t) acc[t] = zero;

    const bf16x8* wfv = (const bf16x8*)Wf;
    int rowL = (wv >> 1) * 16 + (lane & 15);   // row-tile shared by 2 waves
    int ntBase = (wv & 1) * 4;                 // column-half split
    int q = lane >> 4;
    int swz = (rowL & 7) << 4;
#pragma unroll
    for (int ks = 0; ks < 4; ++ks) {
        int colb = ks * 128 + q * 32;
        float4 lo = *(const float4*)&smem[(rowL * 512 + colb) ^ swz];
        float4 hi = *(const float4*)&smem[(rowL * 512 + colb + 16) ^ swz];
        bf16x8 a;
        a[0] = (short)f2bf(lo.x); a[1] = (short)f2bf(lo.y);
        a[2] = (short)f2bf(lo.z); a[3] = (short)f2bf(lo.w);
        a[4] = (short)f2bf(hi.x); a[5] = (short)f2bf(hi.y);
        a[6] = (short)f2bf(hi.z); a[7] = (short)f2bf(hi.w);
#pragma unroll
        for (int nt2 = 0; nt2 < 4; ++nt2) {
            int nt = ntBase + nt2;
            bf16x8 bfr = wfv[(nt * 4 + ks) * 64 + lane];
            acc[nt2] = __builtin_amdgcn_mfma_f32_16x16x32_bf16(a, bfr, acc[nt2], 0, 0, 0);
        }
    }

    int orow_base = blockRow + (wv >> 1) * 16 + q * 4;
#pragma unroll
    for (int r = 0; r < 4; ++r) {
        int orow = orow_base + r;
        if (orow < n) {
#pragma unroll
            for (int nt2 = 0; nt2 < 4; ++nt2) {
                int nt = ntBase + nt2;
                y[(size_t)orow * DCH + nt * 16 + (lane & 15)] = f2bf(acc[nt2][r]);
            }
        }
    }
}

// -------- launch 1: part (blocks < nPart, R5 re-pack form) || gemm half A ----
// Gemm is split across launches 1 and 2 so BOTH sort phases overlap with
// BW-bound gemm work (previously all of gemm hid only csr while part ran on
// a ~62%-idle machine).
__global__ __launch_bounds__(512) void k_pga(const int* __restrict__ row,
                                             const int* __restrict__ col,
                                             unsigned int* __restrict__ coarse,
                                             int* __restrict__ gcount,
                                             const float* __restrict__ x,
                                             const unsigned short* __restrict__ Wf,
                                             unsigned short* __restrict__ y,
                                             int E, int B, int nPart, int n) {
    __shared__ uint4 smem4[2048];               // 32 KB union
    char* smem = (char*)smem4;

    int tid = threadIdx.x;
    int wv = tid >> 6, lane = tid & 63;

    if (blockIdx.x >= nPart) {
        gemm_tile(smem, x, Wf, y, (blockIdx.x - nPart) * 64, n, wv, lane);
        return;
    }

    // ---- part: coarse bucket partition (R5-verified re-pack form) ----
    unsigned int* spack   = (unsigned int*)smem;            // 16 KB
    unsigned short* sbuck = (unsigned short*)(smem + 16384);// 8 KB
    int* hist  = (int*)(smem + 24576);                      // 2 KB (reused as gb)
    int* basex = (int*)(smem + 26624);                      // 2 KB
    int* curx  = (int*)(smem + 28672);                      // 2 KB
    int* wsum  = (int*)(smem + 30720);                      // 32 B
    int* gb = hist;

    int base_e = blockIdx.x * T_PART;
    int tileCnt = min(T_PART, E - base_e);

    hist[tid] = 0;
    __syncthreads();

    int er[8], ec[8];
#pragma unroll
    for (int i = 0; i < 8; ++i) {
        int e = base_e + tid + i * 512;
        if (e < E) {
            er[i] = row[e];
            ec[i] = col[e];
            atomicAdd(&hist[ec[i] >> 8], 1);
        } else {
            er[i] = -1;
            ec[i] = 0;
        }
    }
    __syncthreads();

    int v = hist[tid];
    int x2 = v;
#pragma unroll
    for (int o = 1; o < 64; o <<= 1) {
        int t = __shfl_up(x2, o, 64);
        if (lane >= o) x2 += t;
    }
    if (lane == 63) wsum[wv] = x2;
    __syncthreads();
    int add = 0;
    for (int w = 0; w < wv; ++w) add += wsum[w];
    int excl = x2 - v + add;
    basex[tid] = excl;
    curx[tid] = excl;
    gb[tid] = (tid < B && v > 0) ? atomicAdd(&gcount[tid], v) : 0;
    __syncthreads();

#pragma unroll
    for (int i = 0; i < 8; ++i) {
        if (er[i] >= 0) {
            int bb = ec[i] >> 8;
            int slot = atomicAdd(&curx[bb], 1);
            spack[slot] = ((unsigned int)er[i] << 8) | (unsigned int)(ec[i] & 255);
            sbuck[slot] = (unsigned short)bb;
        }
    }
    __syncthreads();

    for (int s = tid; s < tileCnt; s += 512) {
        int bb = sbuck[s];
        int dst = gb[bb] + (s - basex[bb]);
        if (dst < CAPC) coarse[(size_t)bb * CAPC + dst] = spack[s];
    }
}

// -------- launch 2: csr (blocks < B) || gemm half B, 32 KB union -------------
__global__ __launch_bounds__(512) void k_cg(const unsigned int* __restrict__ coarse,
                                            const int* __restrict__ gcount,
                                            int* __restrict__ srow,
                                            int* __restrict__ off,
                                            float* __restrict__ dinvf,
                                            const float* __restrict__ x,
                                            const unsigned short* __restrict__ Wf,
                                            unsigned short* __restrict__ y,
                                            int n, int B, int gemmRow0) {
    __shared__ uint4 smem4[2048];               // 32 KB union
    char* smem = (char*)smem4;

    int tid = threadIdx.x;
    int wv = tid >> 6, lane = tid & 63;

    if (blockIdx.x >= B) {
        gemm_tile(smem, x, Wf, y, gemmRow0 + (blockIdx.x - B) * 64, n, wv, lane);
        return;
    }

    // ---------------- csr: bucket -> exact CSR + dinv + offsets ----------
    unsigned int* ent = (unsigned int*)smem;          // 24 KB
    int* h   = (int*)(smem + 24576);                  // 1 KB
    int* cur = (int*)(smem + 25600);                  // 1 KB
    int* red1 = (int*)(smem + 26624);                 // 32 B
    int* red2 = (int*)(smem + 26656);                 // 16 B
    int* bbase_p = (int*)(smem + 26672);

    int b = blockIdx.x;

    int part = 0;
    for (int i = tid; i < b; i += 512) part += gcount[i];
#pragma unroll
    for (int o = 1; o < 64; o <<= 1) part += __shfl_xor(part, o, 64);
    if (lane == 0) red1[wv] = part;
    if (tid < 256) h[tid] = 0;
    __syncthreads();
    if (tid == 0) {
        int s = 0;
        for (int w = 0; w < 8; ++w) s += red1[w];
        bbase_p[0] = s;
    }
    int cntb = min(gcount[b], CAPC);
    for (int s = tid; s < cntb; s += 512) ent[s] = coarse[(size_t)b * CAPC + s];
    __syncthreads();

    for (int s = tid; s < cntb; s += 512) atomicAdd(&h[ent[s] & 255], 1);
    __syncthreads();

    int x2 = 0, v = 0;
    if (tid < 256) {
        v = h[tid];
        x2 = v;
#pragma unroll
        for (int o = 1; o < 64; o <<= 1) {
            int t = __shfl_up(x2, o, 64);
            if (lane >= o) x2 += t;
        }
        if (lane == 63) red2[wv] = x2;
    }
    __syncthreads();
    int bbase = bbase_p[0];
    if (tid < 256) {
        int add = 0;
        for (int w = 0; w < wv; ++w) add += red2[w];
        int excl = x2 - v + add;
        cur[tid] = excl;
        int node = (b << 8) + tid;
        if (node < n) {
            off[node] = bbase + excl;
            dinvf[node] = rsqrtf((float)(v + 1));
        }
    }
    __syncthreads();

    for (int s = tid; s < cntb; s += 512) {
        unsigned int p = ent[s];
        int d = p & 255;
        int slot = atomicAdd(&cur[d], 1);
        srow[bbase + slot] = (int)(p >> 8);
    }
}

// ---------------- per-node gather-aggregate + bias + ReLU --------------------
// One wave per node; quarter-wave q handles edge j+q via uint4 loads; per-edge
// source dinv from L2-resident table via fmaf. shfl_xor(16/32) folds quarters.
__global__ __launch_bounds__(256) void k_agg(const uint4* __restrict__ y4,
                                             const int* __restrict__ srow,
                                             const int* __restrict__ off,
                                             const float* __restrict__ dinv,
                                             const float* __restrict__ b,
                                             float* __restrict__ out, int n, int E) {
    int i = blockIdx.x * 4 + (threadIdx.x >> 6);
    if (i >= n) return;
    int lane = threadIdx.x & 63;
    int q = lane >> 4;
    int l16 = lane & 15;
    int s = off[i];
    int e = (i + 1 < n) ? off[i + 1] : E;
    float di = dinv[i];

    float acc[8];
#pragma unroll
    for (int k = 0; k < 8; ++k) acc[k] = 0.f;

    if (q == 0) {   // self-loop: dinv_i * z_i
        uint4 v = y4[(size_t)i * 16 + l16];
        unsigned int p[4] = {v.x, v.y, v.z, v.w};
#pragma unroll
        for (int t = 0; t < 4; ++t) {
            acc[2 * t]     = fmaf(di, __uint_as_float(p[t] << 16), acc[2 * t]);
            acc[2 * t + 1] = fmaf(di, __uint_as_float(p[t] & 0xffff0000u), acc[2 * t + 1]);
        }
    }

    int j = s;
    for (; j + 16 <= e; j += 16) {
        int s0 = srow[j + q];
        int s1 = srow[j + 4 + q];
        int s2 = srow[j + 8 + q];
        int s3 = srow[j + 12 + q];
        float d0 = dinv[s0], d1 = dinv[s1], d2 = dinv[s2], d3 = dinv[s3];
        uint4 v0 = y4[(size_t)s0 * 16 + l16];
        uint4 v1 = y4[(size_t)s1 * 16 + l16];
        uint4 v2 = y4[(size_t)s2 * 16 + l16];
        uint4 v3 = y4[(size_t)s3 * 16 + l16];
        unsigned int p0[4] = {v0.x, v0.y, v0.z, v0.w};
        unsigned int p1[4] = {v1.x, v1.y, v1.z, v1.w};
        unsigned int p2[4] = {v2.x, v2.y, v2.z, v2.w};
        unsigned int p3[4] = {v3.x, v3.y, v3.z, v3.w};
#pragma unroll
        for (int t = 0; t < 4; ++t) {
            acc[2 * t]     = fmaf(d0, __uint_as_float(p0[t] << 16), acc[2 * t]);
            acc[2 * t + 1] = fmaf(d0, __uint_as_float(p0[t] & 0xffff0000u), acc[2 * t + 1]);
            acc[2 * t]     = fmaf(d1, __uint_as_float(p1[t] << 16), acc[2 * t]);
            acc[2 * t + 1] = fmaf(d1, __uint_as_float(p1[t] & 0xffff0000u), acc[2 * t + 1]);
            acc[2 * t]     = fmaf(d2, __uint_as_float(p2[t] << 16), acc[2 * t]);
            acc[2 * t + 1] = fmaf(d2, __uint_as_float(p2[t] & 0xffff0000u), acc[2 * t + 1]);
            acc[2 * t]     = fmaf(d3, __uint_as_float(p3[t] << 16), acc[2 * t]);
            acc[2 * t + 1] = fmaf(d3, __uint_as_float(p3[t] & 0xffff0000u), acc[2 * t + 1]);
        }
    }
    for (; j + 8 <= e; j += 8) {
        int s0 = srow[j + q];
        int s1 = srow[j + 4 + q];
        float d0 = dinv[s0], d1 = dinv[s1];
        uint4 v0 = y4[(size_t)s0 * 16 + l16];
        uint4 v1 = y4[(size_t)s1 * 16 + l16];
        unsigned int p0[4] = {v0.x, v0.y, v0.z, v0.w};
        unsigned int p1[4] = {v1.x, v1.y, v1.z, v1.w};
#pragma unroll
        for (int t = 0; t < 4; ++t) {
            acc[2 * t]     = fmaf(d0, __uint_as_float(p0[t] << 16), acc[2 * t]);
            acc[2 * t + 1] = fmaf(d0, __uint_as_float(p0[t] & 0xffff0000u), acc[2 * t + 1]);
            acc[2 * t]     = fmaf(d1, __uint_as_float(p1[t] << 16), acc[2 * t]);
            acc[2 * t + 1] = fmaf(d1, __uint_as_float(p1[t] & 0xffff0000u), acc[2 * t + 1]);
        }
    }
    for (; j + 4 <= e; j += 4) {
        int s0 = srow[j + q];
        float d0 = dinv[s0];
        uint4 v0 = y4[(size_t)s0 * 16 + l16];
        unsigned int p0[4] = {v0.x, v0.y, v0.z, v0.w};
#pragma unroll
        for (int t = 0; t < 4; ++t) {
            acc[2 * t]     = fmaf(d0, __uint_as_float(p0[t] << 16), acc[2 * t]);
            acc[2 * t + 1] = fmaf(d0, __uint_as_float(p0[t] & 0xffff0000u), acc[2 * t + 1]);
        }
    }
    if (j + q < e) {
        int s0 = srow[j + q];
        float d0 = dinv[s0];
        uint4 v0 = y4[(size_t)s0 * 16 + l16];
        unsigned int p0[4] = {v0.x, v0.y, v0.z, v0.w};
#pragma unroll
        for (int t = 0; t < 4; ++t) {
            acc[2 * t]     = fmaf(d0, __uint_as_float(p0[t] << 16), acc[2 * t]);
            acc[2 * t + 1] = fmaf(d0, __uint_as_float(p0[t] & 0xffff0000u), acc[2 * t + 1]);
        }
    }

#pragma unroll
    for (int k = 0; k < 8; ++k) {
        acc[k] += __shfl_xor(acc[k], 16, 64);
        acc[k] += __shfl_xor(acc[k], 32, 64);
    }

    if (q == 0) {
        float sc = di;
        int c0 = l16 * 8;
        float4 b0 = *(const float4*)&b[c0];
        float4 b1 = *(const float4*)&b[c0 + 4];
        f32x4 o0, o1;
        o0[0] = fmaxf(fmaf(sc, acc[0], b0.x), 0.f);
        o0[1] = fmaxf(fmaf(sc, acc[1], b0.y), 0.f);
        o0[2] = fmaxf(fmaf(sc, acc[2], b0.z), 0.f);
        o0[3] = fmaxf(fmaf(sc, acc[3], b0.w), 0.f);
        o1[0] = fmaxf(fmaf(sc, acc[4], b1.x), 0.f);
        o1[1] = fmaxf(fmaf(sc, acc[5], b1.y), 0.f);
        o1[2] = fmaxf(fmaf(sc, acc[6], b1.z), 0.f);
        o1[3] = fmaxf(fmaf(sc, acc[7], b1.w), 0.f);
        f32x4* orow = (f32x4*)&out[(size_t)i * DCH + c0];
        __builtin_nontemporal_store(o0, &orow[0]);
        __builtin_nontemporal_store(o1, &orow[1]);
    }
}

extern "C" void kernel_launch(void* const* d_in, const int* in_sizes, int n_in,
                              void* d_out, int out_size, void* d_ws, size_t ws_size,
                              hipStream_t stream) {
    const float* x = (const float*)d_in[0];
    const int* ei  = (const int*)d_in[1];
    const float* W = (const float*)d_in[2];
    const float* b = (const float*)d_in[3];
    float* out = (float*)d_out;

    int n = in_sizes[0] / DCH;     // 100000
    int E = in_sizes[1] / 2;       // 1600000
    const int* row = ei;           // sources
    const int* col = ei + E;       // destinations

    int B = (n + 255) / 256;       // 391 coarse buckets

    char* ws = (char*)d_ws;
    size_t o = 0;
    auto alloc = [&](size_t bytes) -> void* {
        o = (o + 255) & ~(size_t)255;
        void* p = ws + o;
        o += bytes;
        return p;
    };
    float* dinvf = (float*)alloc((size_t)n * 4);
    int* off     = (int*)alloc((size_t)(n + 1) * 4);
    int* gcount  = (int*)alloc((size_t)B * 4);
    int* srow    = (int*)alloc((size_t)E * 4);
    unsigned int* coarse = (unsigned int*)alloc((size_t)B * CAPC * 4);  // 9.6 MB
    unsigned short* Wf = (unsigned short*)alloc((size_t)DCH * DCH * 2);
    unsigned short* y  = (unsigned short*)alloc((size_t)n * DCH * 2);   // 25.6 MB

    int nt = (E + T_PART - 1) / T_PART;        // 391 part blocks
    int gemmBlocks = (n + 63) / 64;            // 1563 gemm blocks
    int gA = gemmBlocks / 2;                   // 781 blocks -> rows [0, 49984)
    int rowsA = gA * 64;                       // 49984
    int gB = (n - rowsA + 63) / 64;            // 782 blocks -> rows [49984, n)

    k_init<<<8, 256, 0, stream>>>(W, Wf, gcount, B);
    k_pga<<<nt + gA, 512, 0, stream>>>(row, col, coarse, gcount,
                                       x, Wf, y, E, B, nt, n);
    k_cg<<<B + gB, 512, 0, stream>>>(coarse, gcount, srow, off, dinvf,
                                     x, Wf, y, n, B, rowsA);
    k_agg<<<(n + 3) / 4, 256, 0, stream>>>((const uint4*)y, srow, off, dinvf,
                                           b, out, n, E);
}